// Round 1
// baseline (493.851 us; speedup 1.0000x reference)
//
#include <hip/hip_runtime.h>
#include <hip/hip_bf16.h>

#define BATCH 4
#define NPTS  8192
#define SPTS  2048
#define C1    128
#define C2    256
#define CIN   384   // C1+C2
#define H0    256
#define H1    128
#define KT    16
#define TS    64

// ---------------- transpose points2 (B,C2,S) -> (B,S,C2) ----------------
__global__ __launch_bounds__(256) void transpose_p2_kernel(
    const float* __restrict__ p2, float* __restrict__ p2t) {
  __shared__ float tile[64][65];
  int b = blockIdx.z;
  int s0 = blockIdx.x * 64, c0 = blockIdx.y * 64;
  const float* src = p2 + (size_t)b * C2 * SPTS;
  float* dst = p2t + (size_t)b * SPTS * C2;
  int t = threadIdx.x;
  int ss = t & 63, cseg = t >> 6;   // cseg 0..3
#pragma unroll
  for (int i = 0; i < 16; i++) {
    int cc = cseg + i * 4;
    tile[cc][ss] = src[(size_t)(c0 + cc) * SPTS + s0 + ss];
  }
  __syncthreads();
  int cc2 = t & 63, sseg = t >> 6;
#pragma unroll
  for (int i = 0; i < 16; i++) {
    int ss2 = sseg + i * 4;
    dst[(size_t)(s0 + ss2) * C2 + c0 + cc2] = tile[cc2][ss2];
  }
}

// ---------------- 3-NN search: one thread per (b,n) ----------------
__global__ __launch_bounds__(256) void knn_kernel(
    const float* __restrict__ xyz1, const float* __restrict__ xyz2,
    int* __restrict__ nidx, float* __restrict__ nw) {
  __shared__ float sx[SPTS], sy[SPTS], sz[SPTS];
  int b = blockIdx.y;
  int n = blockIdx.x * 256 + threadIdx.x;
  const float* x2 = xyz2 + (size_t)b * 3 * SPTS;
  for (int i = threadIdx.x; i < SPTS; i += 256) {
    sx[i] = x2[i];
    sy[i] = x2[SPTS + i];
    sz[i] = x2[2 * SPTS + i];
  }
  __syncthreads();
  const float* x1 = xyz1 + (size_t)b * 3 * NPTS;
  float px = x1[n], py = x1[NPTS + n], pz = x1[2 * NPTS + n];
  float d0 = 3.0e38f, d1 = 3.0e38f, d2 = 3.0e38f;
  int i0 = 0, i1 = 0, i2 = 0;
  for (int s = 0; s < SPTS; s++) {
    float dx = px - sx[s], dy = py - sy[s], dz = pz - sz[s];
    float d = dx * dx + dy * dy + dz * dz;
    if (d < d2) {
      if (d < d1) {
        d2 = d1; i2 = i1;
        if (d < d0) { d1 = d0; i1 = i0; d0 = d; i0 = s; }
        else        { d1 = d;  i1 = s; }
      } else { d2 = d; i2 = s; }
    }
  }
  float r0 = 1.f / (d0 + 1e-8f), r1 = 1.f / (d1 + 1e-8f), r2 = 1.f / (d2 + 1e-8f);
  float rs = 1.f / (r0 + r1 + r2);
  int base = (b * NPTS + n) * 3;
  nidx[base + 0] = i0; nidx[base + 1] = i1; nidx[base + 2] = i2;
  nw[base + 0] = r0 * rs; nw[base + 1] = r1 * rs; nw[base + 2] = r2 * rs;
}

// ---------------- interpolation: write interp (B,N,C2) ----------------
__global__ __launch_bounds__(256) void interp_kernel(
    const float* __restrict__ p2t, const int* __restrict__ nidx,
    const float* __restrict__ nw, float* __restrict__ interp) {
  const int PTS = 8;
  int bid = blockIdx.x;
  int b = bid / (NPTS / PTS);
  int p0 = (bid % (NPTS / PTS)) * PTS;
  int c = threadIdx.x;  // 0..255 == C2
  const float* base = p2t + (size_t)b * SPTS * C2;
#pragma unroll
  for (int k = 0; k < PTS; k++) {
    int p = p0 + k;
    int ib = (b * NPTS + p) * 3;
    int i0 = nidx[ib], i1 = nidx[ib + 1], i2 = nidx[ib + 2];
    float w0v = nw[ib], w1v = nw[ib + 1], w2v = nw[ib + 2];
    float v = w0v * base[(size_t)i0 * C2 + c] +
              w1v * base[(size_t)i1 * C2 + c] +
              w2v * base[(size_t)i2 * C2 + c];
    interp[((size_t)b * NPTS + p) * C2 + c] = v;
  }
}

// ---------------- GEMM1: Y0[b,o,n] = sum_c W0[o,c]*X[b,c,n] + b0[o] ----------------
// X rows 0..127 from points1 (B,C1,N); rows 128..383 from interp (B,N,C2)
__global__ __launch_bounds__(256) void gemm1_kernel(
    const float* __restrict__ points1, const float* __restrict__ interp,
    const float* __restrict__ W, const float* __restrict__ bias,
    float* __restrict__ Y) {
  __shared__ float Ws[KT][TS];
  __shared__ float Xs[KT][TS];
  int b = blockIdx.z;
  int n0 = blockIdx.x * TS;
  int o0 = blockIdx.y * TS;
  int t = threadIdx.x;
  int tc = t & 15, tr = t >> 4;
  float4 acc[4];
#pragma unroll
  for (int i = 0; i < 4; i++) acc[i] = make_float4(0.f, 0.f, 0.f, 0.f);

  const float* p1b = points1 + (size_t)b * C1 * NPTS;
  const float* inb = interp + (size_t)b * NPTS * C2;

  for (int k0 = 0; k0 < CIN; k0 += KT) {
    {
      int oo = t & 63, kseg = t >> 6;
      float4 wv = *(const float4*)(W + (size_t)(o0 + oo) * CIN + k0 + kseg * 4);
      Ws[kseg * 4 + 0][oo] = wv.x;
      Ws[kseg * 4 + 1][oo] = wv.y;
      Ws[kseg * 4 + 2][oo] = wv.z;
      Ws[kseg * 4 + 3][oo] = wv.w;
    }
    if (k0 < C1) {
      int nn = t & 63, kseg = t >> 6;
#pragma unroll
      for (int j = 0; j < 4; j++) {
        int kk = kseg * 4 + j;
        Xs[kk][nn] = p1b[(size_t)(k0 + kk) * NPTS + n0 + nn];
      }
    } else {
      int nn = t >> 2, kk4 = (t & 3) * 4;
      float4 xv = *(const float4*)(inb + (size_t)(n0 + nn) * C2 + (k0 - C1) + kk4);
      Xs[kk4 + 0][nn] = xv.x;
      Xs[kk4 + 1][nn] = xv.y;
      Xs[kk4 + 2][nn] = xv.z;
      Xs[kk4 + 3][nn] = xv.w;
    }
    __syncthreads();
#pragma unroll
    for (int kk = 0; kk < KT; kk++) {
      float4 av = *(const float4*)&Ws[kk][tr * 4];
      float4 bv = *(const float4*)&Xs[kk][tc * 4];
      acc[0].x += av.x * bv.x; acc[0].y += av.x * bv.y; acc[0].z += av.x * bv.z; acc[0].w += av.x * bv.w;
      acc[1].x += av.y * bv.x; acc[1].y += av.y * bv.y; acc[1].z += av.y * bv.z; acc[1].w += av.y * bv.w;
      acc[2].x += av.z * bv.x; acc[2].y += av.z * bv.y; acc[2].z += av.z * bv.z; acc[2].w += av.z * bv.w;
      acc[3].x += av.w * bv.x; acc[3].y += av.w * bv.y; acc[3].z += av.w * bv.z; acc[3].w += av.w * bv.w;
    }
    __syncthreads();
  }
  float* yb = Y + (size_t)b * H0 * NPTS;
#pragma unroll
  for (int i = 0; i < 4; i++) {
    int o = o0 + tr * 4 + i;
    float bv = bias[o];
    float4 r = acc[i];
    r.x += bv; r.y += bv; r.z += bv; r.w += bv;
    *(float4*)(yb + (size_t)o * NPTS + n0 + tc * 4) = r;
  }
}

// ---------------- BN stats: per-channel mean/var -> scale a, shift s ----------------
template <int C>
__global__ __launch_bounds__(256) void bn_stats_kernel(
    const float* __restrict__ Y, const float* __restrict__ gamma,
    const float* __restrict__ beta, float* __restrict__ a, float* __restrict__ s) {
  int o = blockIdx.x;
  int t = threadIdx.x;
  float sum = 0.f, sq = 0.f;
  for (int b = 0; b < BATCH; b++) {
    const float* p = Y + ((size_t)b * C + o) * NPTS;
    for (int n = t * 4; n < NPTS; n += 1024) {
      float4 v = *(const float4*)(p + n);
      sum += v.x + v.y + v.z + v.w;
      sq += v.x * v.x + v.y * v.y + v.z * v.z + v.w * v.w;
    }
  }
  __shared__ float r1[256], r2[256];
  r1[t] = sum; r2[t] = sq;
  __syncthreads();
  for (int off = 128; off > 0; off >>= 1) {
    if (t < off) { r1[t] += r1[t + off]; r2[t] += r2[t + off]; }
    __syncthreads();
  }
  if (t == 0) {
    float inv = 1.f / (float)(BATCH * NPTS);
    float mean = r1[0] * inv;
    float var = r2[0] * inv - mean * mean;
    float ia = gamma[o] * rsqrtf(var + 1e-5f);
    a[o] = ia;
    s[o] = beta[o] - mean * ia;
  }
}

// ---------------- GEMM2: Y1[b,o,n] = sum_c W1[o,c]*relu(a0[c]*Y0[b,c,n]+s0[c]) + b1[o] ----------------
__global__ __launch_bounds__(256) void gemm2_kernel(
    const float* __restrict__ Y0, const float* __restrict__ a0,
    const float* __restrict__ s0, const float* __restrict__ W,
    const float* __restrict__ bias, float* __restrict__ Y) {
  __shared__ float Ws[KT][TS];
  __shared__ float Xs[KT][TS];
  int b = blockIdx.z;
  int n0 = blockIdx.x * TS;
  int o0 = blockIdx.y * TS;
  int t = threadIdx.x;
  int tc = t & 15, tr = t >> 4;
  float4 acc[4];
#pragma unroll
  for (int i = 0; i < 4; i++) acc[i] = make_float4(0.f, 0.f, 0.f, 0.f);

  const float* y0b = Y0 + (size_t)b * H0 * NPTS;

  for (int k0 = 0; k0 < H0; k0 += KT) {
    {
      int oo = t & 63, kseg = t >> 6;
      float4 wv = *(const float4*)(W + (size_t)(o0 + oo) * H0 + k0 + kseg * 4);
      Ws[kseg * 4 + 0][oo] = wv.x;
      Ws[kseg * 4 + 1][oo] = wv.y;
      Ws[kseg * 4 + 2][oo] = wv.z;
      Ws[kseg * 4 + 3][oo] = wv.w;
    }
    {
      int nn = t & 63, kseg = t >> 6;
#pragma unroll
      for (int j = 0; j < 4; j++) {
        int kk = kseg * 4 + j;
        int cidx = k0 + kk;
        float v = a0[cidx] * y0b[(size_t)cidx * NPTS + n0 + nn] + s0[cidx];
        Xs[kk][nn] = fmaxf(v, 0.f);
      }
    }
    __syncthreads();
#pragma unroll
    for (int kk = 0; kk < KT; kk++) {
      float4 av = *(const float4*)&Ws[kk][tr * 4];
      float4 bv = *(const float4*)&Xs[kk][tc * 4];
      acc[0].x += av.x * bv.x; acc[0].y += av.x * bv.y; acc[0].z += av.x * bv.z; acc[0].w += av.x * bv.w;
      acc[1].x += av.y * bv.x; acc[1].y += av.y * bv.y; acc[1].z += av.y * bv.z; acc[1].w += av.y * bv.w;
      acc[2].x += av.z * bv.x; acc[2].y += av.z * bv.y; acc[2].z += av.z * bv.z; acc[2].w += av.z * bv.w;
      acc[3].x += av.w * bv.x; acc[3].y += av.w * bv.y; acc[3].z += av.w * bv.z; acc[3].w += av.w * bv.w;
    }
    __syncthreads();
  }
  float* yb = Y + (size_t)b * H1 * NPTS;
#pragma unroll
  for (int i = 0; i < 4; i++) {
    int o = o0 + tr * 4 + i;
    float bv = bias[o];
    float4 r = acc[i];
    r.x += bv; r.y += bv; r.z += bv; r.w += bv;
    *(float4*)(yb + (size_t)o * NPTS + n0 + tc * 4) = r;
  }
}

// ---------------- final BN+ReLU in-place on d_out ----------------
__global__ __launch_bounds__(256) void bn_apply_kernel(
    float* __restrict__ Y, const float* __restrict__ a, const float* __restrict__ s) {
  int idx = blockIdx.x * 256 + threadIdx.x;
  int i = idx * 4;
  int c = (i >> 13) & (H1 - 1);  // (i / NPTS) % H1
  float ia = a[c], sh = s[c];
  float4 v = *(float4*)(Y + i);
  v.x = fmaxf(v.x * ia + sh, 0.f);
  v.y = fmaxf(v.y * ia + sh, 0.f);
  v.z = fmaxf(v.z * ia + sh, 0.f);
  v.w = fmaxf(v.w * ia + sh, 0.f);
  *(float4*)(Y + i) = v;
}

extern "C" void kernel_launch(void* const* d_in, const int* in_sizes, int n_in,
                              void* d_out, int out_size, void* d_ws, size_t ws_size,
                              hipStream_t stream) {
  const float* xyz1    = (const float*)d_in[0];
  const float* xyz2    = (const float*)d_in[1];
  const float* points1 = (const float*)d_in[2];
  const float* points2 = (const float*)d_in[3];
  const float* w0      = (const float*)d_in[4];
  const float* b0      = (const float*)d_in[5];
  const float* gamma0  = (const float*)d_in[6];
  const float* beta0   = (const float*)d_in[7];
  const float* w1      = (const float*)d_in[8];
  const float* b1      = (const float*)d_in[9];
  const float* gamma1  = (const float*)d_in[10];
  const float* beta1   = (const float*)d_in[11];
  float* out = (float*)d_out;

  float* ws = (float*)d_ws;
  float* p2t    = ws;                      // B*S*C2      = 2,097,152
  float* interp = p2t + (size_t)BATCH * SPTS * C2;   // B*N*C2 = 8,388,608
  float* y0     = interp + (size_t)BATCH * NPTS * C2; // B*H0*N = 8,388,608
  int*   nidx   = (int*)(y0 + (size_t)BATCH * H0 * NPTS);  // B*N*3
  float* nw     = (float*)(nidx + (size_t)BATCH * NPTS * 3);
  float* a0     = nw + (size_t)BATCH * NPTS * 3;
  float* s0     = a0 + H0;
  float* a1     = s0 + H0;
  float* s1     = a1 + H1;
  (void)s1; (void)ws_size; (void)in_sizes; (void)n_in; (void)out_size;

  transpose_p2_kernel<<<dim3(SPTS / 64, C2 / 64, BATCH), 256, 0, stream>>>(points2, p2t);
  knn_kernel<<<dim3(NPTS / 256, BATCH), 256, 0, stream>>>(xyz1, xyz2, nidx, nw);
  interp_kernel<<<dim3(BATCH * NPTS / 8), 256, 0, stream>>>(p2t, nidx, nw, interp);
  gemm1_kernel<<<dim3(NPTS / TS, H0 / TS, BATCH), 256, 0, stream>>>(points1, interp, w0, b0, y0);
  bn_stats_kernel<H0><<<H0, 256, 0, stream>>>(y0, gamma0, beta0, a0, s0);
  gemm2_kernel<<<dim3(NPTS / TS, H1 / TS, BATCH), 256, 0, stream>>>(y0, a0, s0, w1, b1, out);
  bn_stats_kernel<H1><<<H1, 256, 0, stream>>>(out, gamma1, beta1, a1, s1);
  bn_apply_kernel<<<dim3(BATCH * H1 * NPTS / 1024), 256, 0, stream>>>(out, a1, s1);
}

// Round 2
// 323.838 us; speedup vs baseline: 1.5250x; 1.5250x over previous
//
#include <hip/hip_runtime.h>
#include <hip/hip_bf16.h>

#define BATCH 4
#define NPTS  8192
#define SPTS  2048
#define C1    128
#define C2    256
#define CIN   384   // C1+C2
#define H0    256
#define H1    128
#define KT    16
#define TS    64

// ---------------- transpose points2 (B,C2,S) -> (B,S,C2) ----------------
__global__ __launch_bounds__(256) void transpose_p2_kernel(
    const float* __restrict__ p2, float* __restrict__ p2t) {
  __shared__ float tile[64][65];
  int b = blockIdx.z;
  int s0 = blockIdx.x * 64, c0 = blockIdx.y * 64;
  const float* src = p2 + (size_t)b * C2 * SPTS;
  float* dst = p2t + (size_t)b * SPTS * C2;
  int t = threadIdx.x;
  int ss = t & 63, cseg = t >> 6;   // cseg 0..3
#pragma unroll
  for (int i = 0; i < 16; i++) {
    int cc = cseg + i * 4;
    tile[cc][ss] = src[(size_t)(c0 + cc) * SPTS + s0 + ss];
  }
  __syncthreads();
  int cc2 = t & 63, sseg = t >> 6;
#pragma unroll
  for (int i = 0; i < 16; i++) {
    int ss2 = sseg + i * 4;
    dst[(size_t)(s0 + ss2) * C2 + c0 + cc2] = tile[cc2][ss2];
  }
}

// ---------------- prepack xyz2 (B,3,S) -> float4 (B,S) ----------------
__global__ __launch_bounds__(256) void prepack_xyz2_kernel(
    const float* __restrict__ xyz2, float4* __restrict__ xp) {
  int idx = blockIdx.x * 256 + threadIdx.x;  // b*SPTS + s
  int b = idx >> 11;                          // SPTS = 2048
  int s = idx & (SPTS - 1);
  const float* x2 = xyz2 + (size_t)b * 3 * SPTS;
  xp[idx] = make_float4(x2[s], x2[SPTS + s], x2[2 * SPTS + s], 0.f);
}

// ---------------- 3-NN search v2 ----------------
// Block: 256 threads = 4 waves. Each block: 64 queries of one batch.
// Wave w scans candidate chunk [w*512, (w+1)*512) with wave-uniform loads,
// branchless top-3 insertion; chunks merged through LDS.
__global__ __launch_bounds__(256) void knn_kernel(
    const float* __restrict__ xyz1, const float4* __restrict__ xp,
    int* __restrict__ nidx, float* __restrict__ nw) {
  int b = blockIdx.y;
  int t = threadIdx.x;
  int lane = t & 63;
  int chunk = __builtin_amdgcn_readfirstlane(t >> 6);  // wave-uniform 0..3
  int n = blockIdx.x * 64 + lane;
  const float* x1 = xyz1 + (size_t)b * 3 * NPTS;
  float px = x1[n], py = x1[NPTS + n], pz = x1[2 * NPTS + n];

  const int CHUNK = SPTS / 4;  // 512
  int sbase = chunk * CHUNK;
  const float4* cp = xp + (size_t)b * SPTS + sbase;

  float d0 = 3e38f, d1 = 3e38f, d2 = 3e38f;
  int i0 = 0, i1 = 0, i2 = 0;
#pragma unroll 4
  for (int j = 0; j < CHUNK; j++) {
    float4 c = cp[j];  // wave-uniform address -> scalar/broadcast load
    float dx = px - c.x, dy = py - c.y, dz = pz - c.z;
    float d = dx * dx + dy * dy + dz * dz;
    int s = sbase + j;
    bool lt0 = d < d0, lt1 = d < d1, lt2 = d < d2;
    i2 = lt1 ? i1 : (lt2 ? s : i2);
    d2 = lt1 ? d1 : (lt2 ? d : d2);
    i1 = lt0 ? i0 : (lt1 ? s : i1);
    d1 = lt0 ? d0 : (lt1 ? d : d1);
    i0 = lt0 ? s : i0;
    d0 = lt0 ? d : d0;
  }

  __shared__ float dsh[4][64][3];
  __shared__ int   ish[4][64][3];
  dsh[chunk][lane][0] = d0; dsh[chunk][lane][1] = d1; dsh[chunk][lane][2] = d2;
  ish[chunk][lane][0] = i0; ish[chunk][lane][1] = i1; ish[chunk][lane][2] = i2;
  __syncthreads();

  if (t < 64) {
    float e0 = 3e38f, e1 = 3e38f, e2 = 3e38f;
    int j0 = 0, j1 = 0, j2 = 0;
#pragma unroll
    for (int c = 0; c < 4; c++) {
#pragma unroll
      for (int k = 0; k < 3; k++) {
        float d = dsh[c][t][k];
        int s = ish[c][t][k];
        bool lt0 = d < e0, lt1 = d < e1, lt2 = d < e2;
        j2 = lt1 ? j1 : (lt2 ? s : j2);
        e2 = lt1 ? e1 : (lt2 ? d : e2);
        j1 = lt0 ? j0 : (lt1 ? s : j1);
        e1 = lt0 ? e0 : (lt1 ? d : e1);
        j0 = lt0 ? s : j0;
        e0 = lt0 ? d : e0;
      }
    }
    float r0 = 1.f / (e0 + 1e-8f), r1 = 1.f / (e1 + 1e-8f), r2 = 1.f / (e2 + 1e-8f);
    float rs = 1.f / (r0 + r1 + r2);
    int base = (b * NPTS + n) * 3;
    nidx[base + 0] = j0; nidx[base + 1] = j1; nidx[base + 2] = j2;
    nw[base + 0] = r0 * rs; nw[base + 1] = r1 * rs; nw[base + 2] = r2 * rs;
  }
}

// ---------------- interpolation: write interp (B,N,C2) ----------------
__global__ __launch_bounds__(256) void interp_kernel(
    const float* __restrict__ p2t, const int* __restrict__ nidx,
    const float* __restrict__ nw, float* __restrict__ interp) {
  const int PTS = 8;
  int bid = blockIdx.x;
  int b = bid / (NPTS / PTS);
  int p0 = (bid % (NPTS / PTS)) * PTS;
  int c = threadIdx.x;  // 0..255 == C2
  const float* base = p2t + (size_t)b * SPTS * C2;
#pragma unroll
  for (int k = 0; k < PTS; k++) {
    int p = p0 + k;
    int ib = (b * NPTS + p) * 3;
    int i0 = nidx[ib], i1 = nidx[ib + 1], i2 = nidx[ib + 2];
    float w0v = nw[ib], w1v = nw[ib + 1], w2v = nw[ib + 2];
    float v = w0v * base[(size_t)i0 * C2 + c] +
              w1v * base[(size_t)i1 * C2 + c] +
              w2v * base[(size_t)i2 * C2 + c];
    interp[((size_t)b * NPTS + p) * C2 + c] = v;
  }
}

// ---------------- GEMM1: Y0[b,o,n] = sum_c W0[o,c]*X[b,c,n] + b0[o] ----------------
// X rows 0..127 from points1 (B,C1,N); rows 128..383 from interp (B,N,C2)
__global__ __launch_bounds__(256) void gemm1_kernel(
    const float* __restrict__ points1, const float* __restrict__ interp,
    const float* __restrict__ W, const float* __restrict__ bias,
    float* __restrict__ Y) {
  __shared__ float Ws[KT][TS];
  __shared__ float Xs[KT][TS];
  int b = blockIdx.z;
  int n0 = blockIdx.x * TS;
  int o0 = blockIdx.y * TS;
  int t = threadIdx.x;
  int tc = t & 15, tr = t >> 4;
  float4 acc[4];
#pragma unroll
  for (int i = 0; i < 4; i++) acc[i] = make_float4(0.f, 0.f, 0.f, 0.f);

  const float* p1b = points1 + (size_t)b * C1 * NPTS;
  const float* inb = interp + (size_t)b * NPTS * C2;

  for (int k0 = 0; k0 < CIN; k0 += KT) {
    {
      int oo = t & 63, kseg = t >> 6;
      float4 wv = *(const float4*)(W + (size_t)(o0 + oo) * CIN + k0 + kseg * 4);
      Ws[kseg * 4 + 0][oo] = wv.x;
      Ws[kseg * 4 + 1][oo] = wv.y;
      Ws[kseg * 4 + 2][oo] = wv.z;
      Ws[kseg * 4 + 3][oo] = wv.w;
    }
    if (k0 < C1) {
      int nn = t & 63, kseg = t >> 6;
#pragma unroll
      for (int j = 0; j < 4; j++) {
        int kk = kseg * 4 + j;
        Xs[kk][nn] = p1b[(size_t)(k0 + kk) * NPTS + n0 + nn];
      }
    } else {
      int nn = t >> 2, kk4 = (t & 3) * 4;
      float4 xv = *(const float4*)(inb + (size_t)(n0 + nn) * C2 + (k0 - C1) + kk4);
      Xs[kk4 + 0][nn] = xv.x;
      Xs[kk4 + 1][nn] = xv.y;
      Xs[kk4 + 2][nn] = xv.z;
      Xs[kk4 + 3][nn] = xv.w;
    }
    __syncthreads();
#pragma unroll
    for (int kk = 0; kk < KT; kk++) {
      float4 av = *(const float4*)&Ws[kk][tr * 4];
      float4 bv = *(const float4*)&Xs[kk][tc * 4];
      acc[0].x += av.x * bv.x; acc[0].y += av.x * bv.y; acc[0].z += av.x * bv.z; acc[0].w += av.x * bv.w;
      acc[1].x += av.y * bv.x; acc[1].y += av.y * bv.y; acc[1].z += av.y * bv.z; acc[1].w += av.y * bv.w;
      acc[2].x += av.z * bv.x; acc[2].y += av.z * bv.y; acc[2].z += av.z * bv.z; acc[2].w += av.z * bv.w;
      acc[3].x += av.w * bv.x; acc[3].y += av.w * bv.y; acc[3].z += av.w * bv.z; acc[3].w += av.w * bv.w;
    }
    __syncthreads();
  }
  float* yb = Y + (size_t)b * H0 * NPTS;
#pragma unroll
  for (int i = 0; i < 4; i++) {
    int o = o0 + tr * 4 + i;
    float bv = bias[o];
    float4 r = acc[i];
    r.x += bv; r.y += bv; r.z += bv; r.w += bv;
    *(float4*)(yb + (size_t)o * NPTS + n0 + tc * 4) = r;
  }
}

// ---------------- BN stats: per-channel mean/var -> scale a, shift s ----------------
template <int C>
__global__ __launch_bounds__(256) void bn_stats_kernel(
    const float* __restrict__ Y, const float* __restrict__ gamma,
    const float* __restrict__ beta, float* __restrict__ a, float* __restrict__ s) {
  int o = blockIdx.x;
  int t = threadIdx.x;
  float sum = 0.f, sq = 0.f;
  for (int b = 0; b < BATCH; b++) {
    const float* p = Y + ((size_t)b * C + o) * NPTS;
    for (int n = t * 4; n < NPTS; n += 1024) {
      float4 v = *(const float4*)(p + n);
      sum += v.x + v.y + v.z + v.w;
      sq += v.x * v.x + v.y * v.y + v.z * v.z + v.w * v.w;
    }
  }
  __shared__ float r1[256], r2[256];
  r1[t] = sum; r2[t] = sq;
  __syncthreads();
  for (int off = 128; off > 0; off >>= 1) {
    if (t < off) { r1[t] += r1[t + off]; r2[t] += r2[t + off]; }
    __syncthreads();
  }
  if (t == 0) {
    float inv = 1.f / (float)(BATCH * NPTS);
    float mean = r1[0] * inv;
    float var = r2[0] * inv - mean * mean;
    float ia = gamma[o] * rsqrtf(var + 1e-5f);
    a[o] = ia;
    s[o] = beta[o] - mean * ia;
  }
}

// ---------------- GEMM2: Y1[b,o,n] = sum_c W1[o,c]*relu(a0[c]*Y0[b,c,n]+s0[c]) + b1[o] ----------------
__global__ __launch_bounds__(256) void gemm2_kernel(
    const float* __restrict__ Y0, const float* __restrict__ a0,
    const float* __restrict__ s0, const float* __restrict__ W,
    const float* __restrict__ bias, float* __restrict__ Y) {
  __shared__ float Ws[KT][TS];
  __shared__ float Xs[KT][TS];
  int b = blockIdx.z;
  int n0 = blockIdx.x * TS;
  int o0 = blockIdx.y * TS;
  int t = threadIdx.x;
  int tc = t & 15, tr = t >> 4;
  float4 acc[4];
#pragma unroll
  for (int i = 0; i < 4; i++) acc[i] = make_float4(0.f, 0.f, 0.f, 0.f);

  const float* y0b = Y0 + (size_t)b * H0 * NPTS;

  for (int k0 = 0; k0 < H0; k0 += KT) {
    {
      int oo = t & 63, kseg = t >> 6;
      float4 wv = *(const float4*)(W + (size_t)(o0 + oo) * H0 + k0 + kseg * 4);
      Ws[kseg * 4 + 0][oo] = wv.x;
      Ws[kseg * 4 + 1][oo] = wv.y;
      Ws[kseg * 4 + 2][oo] = wv.z;
      Ws[kseg * 4 + 3][oo] = wv.w;
    }
    {
      int nn = t & 63, kseg = t >> 6;
#pragma unroll
      for (int j = 0; j < 4; j++) {
        int kk = kseg * 4 + j;
        int cidx = k0 + kk;
        float v = a0[cidx] * y0b[(size_t)cidx * NPTS + n0 + nn] + s0[cidx];
        Xs[kk][nn] = fmaxf(v, 0.f);
      }
    }
    __syncthreads();
#pragma unroll
    for (int kk = 0; kk < KT; kk++) {
      float4 av = *(const float4*)&Ws[kk][tr * 4];
      float4 bv = *(const float4*)&Xs[kk][tc * 4];
      acc[0].x += av.x * bv.x; acc[0].y += av.x * bv.y; acc[0].z += av.x * bv.z; acc[0].w += av.x * bv.w;
      acc[1].x += av.y * bv.x; acc[1].y += av.y * bv.y; acc[1].z += av.y * bv.z; acc[1].w += av.y * bv.w;
      acc[2].x += av.z * bv.x; acc[2].y += av.z * bv.y; acc[2].z += av.z * bv.z; acc[2].w += av.z * bv.w;
      acc[3].x += av.w * bv.x; acc[3].y += av.w * bv.y; acc[3].z += av.w * bv.z; acc[3].w += av.w * bv.w;
    }
    __syncthreads();
  }
  float* yb = Y + (size_t)b * H1 * NPTS;
#pragma unroll
  for (int i = 0; i < 4; i++) {
    int o = o0 + tr * 4 + i;
    float bv = bias[o];
    float4 r = acc[i];
    r.x += bv; r.y += bv; r.z += bv; r.w += bv;
    *(float4*)(yb + (size_t)o * NPTS + n0 + tc * 4) = r;
  }
}

// ---------------- final BN+ReLU in-place on d_out ----------------
__global__ __launch_bounds__(256) void bn_apply_kernel(
    float* __restrict__ Y, const float* __restrict__ a, const float* __restrict__ s) {
  int idx = blockIdx.x * 256 + threadIdx.x;
  int i = idx * 4;
  int c = (i >> 13) & (H1 - 1);  // (i / NPTS) % H1
  float ia = a[c], sh = s[c];
  float4 v = *(float4*)(Y + i);
  v.x = fmaxf(v.x * ia + sh, 0.f);
  v.y = fmaxf(v.y * ia + sh, 0.f);
  v.z = fmaxf(v.z * ia + sh, 0.f);
  v.w = fmaxf(v.w * ia + sh, 0.f);
  *(float4*)(Y + i) = v;
}

extern "C" void kernel_launch(void* const* d_in, const int* in_sizes, int n_in,
                              void* d_out, int out_size, void* d_ws, size_t ws_size,
                              hipStream_t stream) {
  const float* xyz1    = (const float*)d_in[0];
  const float* xyz2    = (const float*)d_in[1];
  const float* points1 = (const float*)d_in[2];
  const float* points2 = (const float*)d_in[3];
  const float* w0      = (const float*)d_in[4];
  const float* b0      = (const float*)d_in[5];
  const float* gamma0  = (const float*)d_in[6];
  const float* beta0   = (const float*)d_in[7];
  const float* w1      = (const float*)d_in[8];
  const float* b1      = (const float*)d_in[9];
  const float* gamma1  = (const float*)d_in[10];
  const float* beta1   = (const float*)d_in[11];
  float* out = (float*)d_out;

  float* ws = (float*)d_ws;
  float* p2t    = ws;                                   // B*S*C2 = 2,097,152
  float* interp = p2t + (size_t)BATCH * SPTS * C2;      // B*N*C2 = 8,388,608
  float* y0     = interp + (size_t)BATCH * NPTS * C2;   // B*H0*N = 8,388,608
  int*   nidx   = (int*)(y0 + (size_t)BATCH * H0 * NPTS);   // B*N*3
  float* nw     = (float*)(nidx + (size_t)BATCH * NPTS * 3);
  float* a0     = nw + (size_t)BATCH * NPTS * 3;
  float* s0     = a0 + H0;
  float* a1     = s0 + H0;
  float* s1     = a1 + H1;
  float4* xyz2p = (float4*)(s1 + H1);                   // B*S float4 (16B aligned)
  (void)ws_size; (void)in_sizes; (void)n_in; (void)out_size;

  transpose_p2_kernel<<<dim3(SPTS / 64, C2 / 64, BATCH), 256, 0, stream>>>(points2, p2t);
  prepack_xyz2_kernel<<<dim3(BATCH * SPTS / 256), 256, 0, stream>>>(xyz2, xyz2p);
  knn_kernel<<<dim3(NPTS / 64, BATCH), 256, 0, stream>>>(xyz1, xyz2p, nidx, nw);
  interp_kernel<<<dim3(BATCH * NPTS / 8), 256, 0, stream>>>(p2t, nidx, nw, interp);
  gemm1_kernel<<<dim3(NPTS / TS, H0 / TS, BATCH), 256, 0, stream>>>(points1, interp, w0, b0, y0);
  bn_stats_kernel<H0><<<H0, 256, 0, stream>>>(y0, gamma0, beta0, a0, s0);
  gemm2_kernel<<<dim3(NPTS / TS, H1 / TS, BATCH), 256, 0, stream>>>(y0, a0, s0, w1, b1, out);
  bn_stats_kernel<H1><<<H1, 256, 0, stream>>>(out, gamma1, beta1, a1, s1);
  bn_apply_kernel<<<dim3(BATCH * H1 * NPTS / 1024), 256, 0, stream>>>(out, a1, s1);
}

// Round 3
// 237.152 us; speedup vs baseline: 2.0824x; 1.3655x over previous
//
#include <hip/hip_runtime.h>
#include <hip/hip_bf16.h>

#define BATCH 4
#define NPTS  8192
#define SPTS  2048
#define C1    128
#define C2    256
#define CIN   384   // C1+C2
#define H0    256
#define H1    128

typedef __attribute__((ext_vector_type(8))) short bf16x8;
typedef __attribute__((ext_vector_type(4))) float f32x4;

__device__ __forceinline__ unsigned short f2bf(float x) {
  union { float f; unsigned u; } v; v.f = x;
  unsigned r = v.u + 0x7fff + ((v.u >> 16) & 1);   // RNE
  return (unsigned short)(r >> 16);
}
__device__ __forceinline__ float bf2f(unsigned short u) {
  union { unsigned u; float f; } v; v.u = ((unsigned)u) << 16; return v.f;
}

// ---------------- transpose points2 (B,C2,S) -> (B,S,C2) fp32 ----------------
__global__ __launch_bounds__(256) void transpose_p2_kernel(
    const float* __restrict__ p2, float* __restrict__ p2t) {
  __shared__ float tile[64][65];
  int b = blockIdx.z;
  int s0 = blockIdx.x * 64, c0 = blockIdx.y * 64;
  const float* src = p2 + (size_t)b * C2 * SPTS;
  float* dst = p2t + (size_t)b * SPTS * C2;
  int t = threadIdx.x;
  int ss = t & 63, cseg = t >> 6;
#pragma unroll
  for (int i = 0; i < 16; i++) {
    int cc = cseg + i * 4;
    tile[cc][ss] = src[(size_t)(c0 + cc) * SPTS + s0 + ss];
  }
  __syncthreads();
  int cc2 = t & 63, sseg = t >> 6;
#pragma unroll
  for (int i = 0; i < 16; i++) {
    int ss2 = sseg + i * 4;
    dst[(size_t)(s0 + ss2) * C2 + c0 + cc2] = tile[cc2][ss2];
  }
}

// ---------------- prepack xyz2 (B,3,S) -> float4 (B,S) ----------------
__global__ __launch_bounds__(256) void prepack_xyz2_kernel(
    const float* __restrict__ xyz2, float4* __restrict__ xp) {
  int idx = blockIdx.x * 256 + threadIdx.x;
  int b = idx >> 11;
  int s = idx & (SPTS - 1);
  const float* x2 = xyz2 + (size_t)b * 3 * SPTS;
  xp[idx] = make_float4(x2[s], x2[SPTS + s], x2[2 * SPTS + s], 0.f);
}

// ---------------- 3-NN search (R2 version, branchless + chunked) ----------------
__global__ __launch_bounds__(256) void knn_kernel(
    const float* __restrict__ xyz1, const float4* __restrict__ xp,
    int* __restrict__ nidx, float* __restrict__ nw) {
  int b = blockIdx.y;
  int t = threadIdx.x;
  int lane = t & 63;
  int chunk = __builtin_amdgcn_readfirstlane(t >> 6);
  int n = blockIdx.x * 64 + lane;
  const float* x1 = xyz1 + (size_t)b * 3 * NPTS;
  float px = x1[n], py = x1[NPTS + n], pz = x1[2 * NPTS + n];

  const int CHUNK = SPTS / 4;
  int sbase = chunk * CHUNK;
  const float4* cp = xp + (size_t)b * SPTS + sbase;

  float d0 = 3e38f, d1 = 3e38f, d2 = 3e38f;
  int i0 = 0, i1 = 0, i2 = 0;
#pragma unroll 4
  for (int j = 0; j < CHUNK; j++) {
    float4 c = cp[j];
    float dx = px - c.x, dy = py - c.y, dz = pz - c.z;
    float d = dx * dx + dy * dy + dz * dz;
    int s = sbase + j;
    bool lt0 = d < d0, lt1 = d < d1, lt2 = d < d2;
    i2 = lt1 ? i1 : (lt2 ? s : i2);
    d2 = lt1 ? d1 : (lt2 ? d : d2);
    i1 = lt0 ? i0 : (lt1 ? s : i1);
    d1 = lt0 ? d0 : (lt1 ? d : d1);
    i0 = lt0 ? s : i0;
    d0 = lt0 ? d : d0;
  }

  __shared__ float dsh[4][64][3];
  __shared__ int   ish[4][64][3];
  dsh[chunk][lane][0] = d0; dsh[chunk][lane][1] = d1; dsh[chunk][lane][2] = d2;
  ish[chunk][lane][0] = i0; ish[chunk][lane][1] = i1; ish[chunk][lane][2] = i2;
  __syncthreads();

  if (t < 64) {
    float e0 = 3e38f, e1 = 3e38f, e2 = 3e38f;
    int j0 = 0, j1 = 0, j2 = 0;
#pragma unroll
    for (int c = 0; c < 4; c++) {
#pragma unroll
      for (int k = 0; k < 3; k++) {
        float d = dsh[c][t][k];
        int s = ish[c][t][k];
        bool lt0 = d < e0, lt1 = d < e1, lt2 = d < e2;
        j2 = lt1 ? j1 : (lt2 ? s : j2);
        e2 = lt1 ? e1 : (lt2 ? d : e2);
        j1 = lt0 ? j0 : (lt1 ? s : j1);
        e1 = lt0 ? e0 : (lt1 ? d : e1);
        j0 = lt0 ? s : j0;
        e0 = lt0 ? d : e0;
      }
    }
    float r0 = 1.f / (e0 + 1e-8f), r1 = 1.f / (e1 + 1e-8f), r2 = 1.f / (e2 + 1e-8f);
    float rs = 1.f / (r0 + r1 + r2);
    int base = (b * NPTS + n) * 3;
    nidx[base + 0] = j0; nidx[base + 1] = j1; nidx[base + 2] = j2;
    nw[base + 0] = r0 * rs; nw[base + 1] = r1 * rs; nw[base + 2] = r2 * rs;
  }
}

// ---------------- pack points1 (B,C1,N) fp32 -> Xp[b][n][0..127] bf16 ----------------
__global__ __launch_bounds__(256) void pack_p1_kernel(
    const float* __restrict__ p1, unsigned short* __restrict__ Xp) {
  __shared__ unsigned short tile[64][136];  // [n][c], 272B rows (16B aligned)
  int b = blockIdx.y, n0 = blockIdx.x * 64;
  int t = threadIdx.x;
  int nn = t & 63, c4 = t >> 6;
#pragma unroll
  for (int i = 0; i < 32; i++) {
    int c = i * 4 + c4;
    tile[nn][c] = f2bf(p1[((size_t)b * C1 + c) * NPTS + n0 + nn]);
  }
  __syncthreads();
  int n = t >> 2;
#pragma unroll
  for (int j = 0; j < 4; j++) {
    int ch = (t & 3) + j * 4;  // 0..15, 8 ushorts each
    uint4 v = *(const uint4*)&tile[n][ch * 8];
    *(uint4*)&Xp[((size_t)b * NPTS + n0 + n) * CIN + ch * 8] = v;
  }
}

// ---------------- interpolation -> Xp[b][n][128..383] bf16 ----------------
__global__ __launch_bounds__(256) void interp_kernel(
    const float* __restrict__ p2t, const int* __restrict__ nidx,
    const float* __restrict__ nw, unsigned short* __restrict__ Xp) {
  const int PTS = 8;
  int bid = blockIdx.x;
  int b = bid / (NPTS / PTS);
  int p0 = (bid % (NPTS / PTS)) * PTS;
  int c = threadIdx.x;  // 0..255 == C2
  const float* base = p2t + (size_t)b * SPTS * C2;
#pragma unroll
  for (int k = 0; k < PTS; k++) {
    int p = p0 + k;
    int ib = (b * NPTS + p) * 3;
    int i0 = nidx[ib], i1 = nidx[ib + 1], i2 = nidx[ib + 2];
    float w0v = nw[ib], w1v = nw[ib + 1], w2v = nw[ib + 2];
    float v = w0v * base[(size_t)i0 * C2 + c] +
              w1v * base[(size_t)i1 * C2 + c] +
              w2v * base[(size_t)i2 * C2 + c];
    Xp[((size_t)b * NPTS + p) * CIN + C1 + c] = f2bf(v);
  }
}

// ---------------- weights fp32 -> bf16 (Wp0: 256x384, Wp1: 128x256 appended) ----------------
__global__ __launch_bounds__(256) void pack_w_kernel(
    const float* __restrict__ w0, const float* __restrict__ w1,
    unsigned short* __restrict__ Wp) {
  int idx = (blockIdx.x * 256 + threadIdx.x) * 4;
  const float* src = (idx < H0 * CIN) ? (w0 + idx) : (w1 + (idx - H0 * CIN));
  float4 v = *(const float4*)src;
  ushort4 o;
  o.x = f2bf(v.x); o.y = f2bf(v.y); o.z = f2bf(v.z); o.w = f2bf(v.w);
  *(ushort4*)(Wp + idx) = o;
}

// ---------------- MFMA GEMM: Y[b,o,n] = sum_k A[o,k]*X[b,n,k] + bias[o] ----------------
// A: (MT,KD) bf16 k-contig; X: (B,NPTS,KD) bf16 k-contig; Y: (B,MT,NPTS) bf16 or fp32
template <int MT, int KD, bool OUT_BF16>
__global__ __launch_bounds__(256) void mfma_gemm_kernel(
    const unsigned short* __restrict__ A, const unsigned short* __restrict__ X,
    const float* __restrict__ bias, void* __restrict__ Yv) {
  __shared__ unsigned short As[128 * 32];
  __shared__ unsigned short Bs[128 * 32];
  int b = blockIdx.z;
  int n0 = blockIdx.x * 128;
  int o0 = blockIdx.y * 128;
  int t = threadIdx.x;
  int lane = t & 63;
  int w = __builtin_amdgcn_readfirstlane(t >> 6);
  int mhalf = (w & 1) * 64, nhalf = (w >> 1) * 64;
  const unsigned short* Xb = X + (size_t)b * NPTS * KD;

  f32x4 acc[4][4] = {};

  int rA = lane >> 2;          // 0..15 row within 16-row stripe
  int cofs = (lane & 3) * 8;   // element offset (8 bf16 = 16B)

  for (int k0 = 0; k0 < KD; k0 += 32) {
#pragma unroll
    for (int q = 0; q < 2; q++) {
      int r0 = w * 32 + q * 16;
      const unsigned short* ga = A + (size_t)(o0 + r0 + rA) * KD + k0 + cofs;
      __builtin_amdgcn_global_load_lds(
          (const __attribute__((address_space(1))) void*)ga,
          (__attribute__((address_space(3))) void*)(As + r0 * 32), 16, 0, 0);
      const unsigned short* gb = Xb + (size_t)(n0 + r0 + rA) * KD + k0 + cofs;
      __builtin_amdgcn_global_load_lds(
          (const __attribute__((address_space(1))) void*)gb,
          (__attribute__((address_space(3))) void*)(Bs + r0 * 32), 16, 0, 0);
    }
    __syncthreads();   // drains vmcnt -> LDS tiles complete

    bf16x8 af[4], bfr[4];
    int mi = lane & 15, kq = (lane >> 4) * 8;
#pragma unroll
    for (int i = 0; i < 4; i++) {
      af[i]  = *(const bf16x8*)(As + (mhalf + i * 16 + mi) * 32 + kq);
      bfr[i] = *(const bf16x8*)(Bs + (nhalf + i * 16 + mi) * 32 + kq);
    }
#pragma unroll
    for (int mt = 0; mt < 4; mt++)
#pragma unroll
      for (int nt = 0; nt < 4; nt++)
        acc[mt][nt] = __builtin_amdgcn_mfma_f32_16x16x32_bf16(
            af[mt], bfr[nt], acc[mt][nt], 0, 0, 0);
    __syncthreads();   // all reads done before next staging overwrites LDS
  }

  // epilogue: D[m][n]: col n = lane&15, row m = (lane>>4)*4 + r
  int mi = lane & 15;
  int rq = (lane >> 4) * 4;
#pragma unroll
  for (int mt = 0; mt < 4; mt++) {
#pragma unroll
    for (int r = 0; r < 4; r++) {
      int m = o0 + mhalf + mt * 16 + rq + r;
      float bv = bias[m];
#pragma unroll
      for (int nt = 0; nt < 4; nt++) {
        int n = n0 + nhalf + nt * 16 + mi;
        float v = acc[mt][nt][r] + bv;
        if constexpr (OUT_BF16) {
          unsigned short* Y = (unsigned short*)Yv + (size_t)b * MT * NPTS;
          Y[(size_t)m * NPTS + n] = f2bf(v);
        } else {
          float* Y = (float*)Yv + (size_t)b * MT * NPTS;
          Y[(size_t)m * NPTS + n] = v;
        }
      }
    }
  }
}

// ---------------- BN stats over bf16 (B,C,N): per-channel a,s ----------------
template <int C>
__global__ __launch_bounds__(256) void bn_stats_bf16_kernel(
    const unsigned short* __restrict__ Y, const float* __restrict__ gamma,
    const float* __restrict__ beta, float* __restrict__ a, float* __restrict__ s) {
  int o = blockIdx.x;
  int t = threadIdx.x;
  float sum = 0.f, sq = 0.f;
  for (int b = 0; b < BATCH; b++) {
    const unsigned short* p = Y + ((size_t)b * C + o) * NPTS;
    for (int n = t * 4; n < NPTS; n += 1024) {
      ushort4 v = *(const ushort4*)(p + n);
      float x0 = bf2f(v.x), x1 = bf2f(v.y), x2 = bf2f(v.z), x3 = bf2f(v.w);
      sum += x0 + x1 + x2 + x3;
      sq += x0 * x0 + x1 * x1 + x2 * x2 + x3 * x3;
    }
  }
  __shared__ float r1[256], r2[256];
  r1[t] = sum; r2[t] = sq;
  __syncthreads();
  for (int off = 128; off > 0; off >>= 1) {
    if (t < off) { r1[t] += r1[t + off]; r2[t] += r2[t + off]; }
    __syncthreads();
  }
  if (t == 0) {
    float inv = 1.f / (float)(BATCH * NPTS);
    float mean = r1[0] * inv;
    float var = r2[0] * inv - mean * mean;
    float ia = gamma[o] * rsqrtf(var + 1e-5f);
    a[o] = ia;
    s[o] = beta[o] - mean * ia;
  }
}

// ---------------- BN stats over fp32 (B,C,N) ----------------
template <int C>
__global__ __launch_bounds__(256) void bn_stats_kernel(
    const float* __restrict__ Y, const float* __restrict__ gamma,
    const float* __restrict__ beta, float* __restrict__ a, float* __restrict__ s) {
  int o = blockIdx.x;
  int t = threadIdx.x;
  float sum = 0.f, sq = 0.f;
  for (int b = 0; b < BATCH; b++) {
    const float* p = Y + ((size_t)b * C + o) * NPTS;
    for (int n = t * 4; n < NPTS; n += 1024) {
      float4 v = *(const float4*)(p + n);
      sum += v.x + v.y + v.z + v.w;
      sq += v.x * v.x + v.y * v.y + v.z * v.z + v.w * v.w;
    }
  }
  __shared__ float r1[256], r2[256];
  r1[t] = sum; r2[t] = sq;
  __syncthreads();
  for (int off = 128; off > 0; off >>= 1) {
    if (t < off) { r1[t] += r1[t + off]; r2[t] += r2[t + off]; }
    __syncthreads();
  }
  if (t == 0) {
    float inv = 1.f / (float)(BATCH * NPTS);
    float mean = r1[0] * inv;
    float var = r2[0] * inv - mean * mean;
    float ia = gamma[o] * rsqrtf(var + 1e-5f);
    a[o] = ia;
    s[o] = beta[o] - mean * ia;
  }
}

// ---------------- BN0 apply + ReLU + transpose: Y0 (B,H0,N) bf16 -> X1 (B,N,H0) bf16 ----------------
__global__ __launch_bounds__(256) void bn0_apply_kernel(
    const unsigned short* __restrict__ Y0, const float* __restrict__ a,
    const float* __restrict__ s, unsigned short* __restrict__ X1) {
  __shared__ unsigned short tile[64][80];  // [n][o], 160B rows (16B aligned)
  int b = blockIdx.z, o0 = blockIdx.y * 64, n0 = blockIdx.x * 64;
  int t = threadIdx.x;
  int nn = t & 63, o4 = t >> 6;
#pragma unroll
  for (int i = 0; i < 16; i++) {
    int o = i * 4 + o4;
    float v = bf2f(Y0[((size_t)b * H0 + o0 + o) * NPTS + n0 + nn]);
    v = fmaxf(v * a[o0 + o] + s[o0 + o], 0.f);
    tile[nn][o] = f2bf(v);
  }
  __syncthreads();
  int n = t >> 2;
#pragma unroll
  for (int j = 0; j < 2; j++) {
    int ch = (t & 3) + j * 4;  // 0..7, 8 ushorts each
    uint4 v = *(const uint4*)&tile[n][ch * 8];
    *(uint4*)&X1[((size_t)b * NPTS + n0 + n) * H0 + o0 + ch * 8] = v;
  }
}

// ---------------- final BN+ReLU in-place on d_out ----------------
__global__ __launch_bounds__(256) void bn_apply_kernel(
    float* __restrict__ Y, const float* __restrict__ a, const float* __restrict__ s) {
  int idx = blockIdx.x * 256 + threadIdx.x;
  int i = idx * 4;
  int c = (i >> 13) & (H1 - 1);
  float ia = a[c], sh = s[c];
  float4 v = *(float4*)(Y + i);
  v.x = fmaxf(v.x * ia + sh, 0.f);
  v.y = fmaxf(v.y * ia + sh, 0.f);
  v.z = fmaxf(v.z * ia + sh, 0.f);
  v.w = fmaxf(v.w * ia + sh, 0.f);
  *(float4*)(Y + i) = v;
}

extern "C" void kernel_launch(void* const* d_in, const int* in_sizes, int n_in,
                              void* d_out, int out_size, void* d_ws, size_t ws_size,
                              hipStream_t stream) {
  const float* xyz1    = (const float*)d_in[0];
  const float* xyz2    = (const float*)d_in[1];
  const float* points1 = (const float*)d_in[2];
  const float* points2 = (const float*)d_in[3];
  const float* w0      = (const float*)d_in[4];
  const float* b0      = (const float*)d_in[5];
  const float* gamma0  = (const float*)d_in[6];
  const float* beta0   = (const float*)d_in[7];
  const float* w1      = (const float*)d_in[8];
  const float* b1      = (const float*)d_in[9];
  const float* gamma1  = (const float*)d_in[10];
  const float* beta1   = (const float*)d_in[11];
  float* out = (float*)d_out;

  char* ws = (char*)d_ws;
  float* p2t = (float*)ws;                    ws += (size_t)BATCH * SPTS * C2 * 4;   // 8.4 MB
  unsigned short* Xp = (unsigned short*)ws;   ws += (size_t)BATCH * NPTS * CIN * 2;  // 25.2 MB
  unsigned short* Y0 = (unsigned short*)ws;   ws += (size_t)BATCH * H0 * NPTS * 2;   // 16.8 MB
  unsigned short* X1 = (unsigned short*)ws;   ws += (size_t)BATCH * NPTS * H0 * 2;   // 16.8 MB
  unsigned short* Wp = (unsigned short*)ws;   ws += (size_t)(H0 * CIN + H1 * H0) * 2;
  int* nidx = (int*)ws;                       ws += (size_t)BATCH * NPTS * 3 * 4;
  float* nw = (float*)ws;                     ws += (size_t)BATCH * NPTS * 3 * 4;
  float4* xyz2p = (float4*)ws;                ws += (size_t)BATCH * SPTS * 16;
  float* a0 = (float*)ws;                     ws += 1024;
  float* s0 = (float*)ws;                     ws += 1024;
  float* a1 = (float*)ws;                     ws += 1024;
  float* s1 = (float*)ws;                     ws += 1024;
  (void)ws_size; (void)in_sizes; (void)n_in; (void)out_size;

  transpose_p2_kernel<<<dim3(SPTS / 64, C2 / 64, BATCH), 256, 0, stream>>>(points2, p2t);
  prepack_xyz2_kernel<<<dim3(BATCH * SPTS / 256), 256, 0, stream>>>(xyz2, xyz2p);
  knn_kernel<<<dim3(NPTS / 64, BATCH), 256, 0, stream>>>(xyz1, xyz2p, nidx, nw);
  pack_p1_kernel<<<dim3(NPTS / 64, BATCH), 256, 0, stream>>>(points1, Xp);
  interp_kernel<<<dim3(BATCH * NPTS / 8), 256, 0, stream>>>(p2t, nidx, nw, Xp);
  pack_w_kernel<<<dim3((H0 * CIN + H1 * H0) / 1024), 256, 0, stream>>>(w0, w1, Wp);

  mfma_gemm_kernel<H0, CIN, true><<<dim3(NPTS / 128, H0 / 128, BATCH), 256, 0, stream>>>(
      Wp, Xp, b0, Y0);
  bn_stats_bf16_kernel<H0><<<H0, 256, 0, stream>>>(Y0, gamma0, beta0, a0, s0);
  bn0_apply_kernel<<<dim3(NPTS / 64, H0 / 64, BATCH), 256, 0, stream>>>(Y0, a0, s0, X1);
  mfma_gemm_kernel<H1, H0, false><<<dim3(NPTS / 128, H1 / 128, BATCH), 256, 0, stream>>>(
      Wp + H0 * CIN, X1, b1, out);
  bn_stats_kernel<H1><<<H1, 256, 0, stream>>>(out, gamma1, beta1, a1, s1);
  bn_apply_kernel<<<dim3(BATCH * H1 * NPTS / 1024), 256, 0, stream>>>(out, a1, s1);
}

// Round 4
// 217.519 us; speedup vs baseline: 2.2704x; 1.0903x over previous
//
#include <hip/hip_runtime.h>
#include <hip/hip_bf16.h>

#define BATCH 4
#define NPTS  8192
#define SPTS  2048
#define C1    128
#define C2    256
#define CIN   384   // C1+C2
#define H0    256
#define H1    128

typedef __attribute__((ext_vector_type(8))) short bf16x8;
typedef __attribute__((ext_vector_type(4))) float f32x4;

__device__ __forceinline__ unsigned short f2bf(float x) {
  union { float f; unsigned u; } v; v.f = x;
  unsigned r = v.u + 0x7fff + ((v.u >> 16) & 1);   // RNE
  return (unsigned short)(r >> 16);
}
__device__ __forceinline__ float bf2f(unsigned short u) {
  union { unsigned u; float f; } v; v.u = ((unsigned)u) << 16; return v.f;
}

// ---------------- transpose points2 (B,C2,S) -> (B,S,C2) fp32 ----------------
__global__ __launch_bounds__(256) void transpose_p2_kernel(
    const float* __restrict__ p2, float* __restrict__ p2t) {
  __shared__ float tile[64][65];
  int b = blockIdx.z;
  int s0 = blockIdx.x * 64, c0 = blockIdx.y * 64;
  const float* src = p2 + (size_t)b * C2 * SPTS;
  float* dst = p2t + (size_t)b * SPTS * C2;
  int t = threadIdx.x;
  int ss = t & 63, cseg = t >> 6;
#pragma unroll
  for (int i = 0; i < 16; i++) {
    int cc = cseg + i * 4;
    tile[cc][ss] = src[(size_t)(c0 + cc) * SPTS + s0 + ss];
  }
  __syncthreads();
  int cc2 = t & 63, sseg = t >> 6;
#pragma unroll
  for (int i = 0; i < 16; i++) {
    int ss2 = sseg + i * 4;
    dst[(size_t)(s0 + ss2) * C2 + c0 + cc2] = tile[cc2][ss2];
  }
}

// ---------------- prepack xyz2 (B,3,S) -> float4 (x,y,z,|c|^2) ----------------
__global__ __launch_bounds__(256) void prepack_xyz2_kernel(
    const float* __restrict__ xyz2, float4* __restrict__ xp) {
  int idx = blockIdx.x * 256 + threadIdx.x;
  int b = idx >> 11;
  int s = idx & (SPTS - 1);
  const float* x2 = xyz2 + (size_t)b * 3 * SPTS;
  float x = x2[s], y = x2[SPTS + s], z = x2[2 * SPTS + s];
  xp[idx] = make_float4(x, y, z, x * x + y * y + z * z);
}

// ---------------- 3-NN search v3: 8 waves/block, 256-candidate chunks ----------------
// Rank on d' = |c|^2 - 2 q.c  (per-query |q|^2 offset preserves ordering).
__global__ __launch_bounds__(512) void knn_kernel(
    const float* __restrict__ xyz1, const float4* __restrict__ xp,
    int* __restrict__ nidx, float* __restrict__ nw) {
  int b = blockIdx.y;
  int t = threadIdx.x;
  int lane = t & 63;
  int chunk = __builtin_amdgcn_readfirstlane(t >> 6);  // wave-uniform 0..7
  int n = blockIdx.x * 64 + lane;
  const float* x1 = xyz1 + (size_t)b * 3 * NPTS;
  float px = x1[n], py = x1[NPTS + n], pz = x1[2 * NPTS + n];

  const int CHUNK = SPTS / 8;  // 256
  int sbase = chunk * CHUNK;
  const float4* cp = xp + (size_t)b * SPTS + sbase;

  float d0 = 3e38f, d1 = 3e38f, d2 = 3e38f;
  int i0 = 0, i1 = 0, i2 = 0;
#pragma unroll 4
  for (int j = 0; j < CHUNK; j++) {
    float4 c = cp[j];  // wave-uniform address -> scalar load
    float qc = px * c.x;
    qc = fmaf(py, c.y, qc);
    qc = fmaf(pz, c.z, qc);
    float d = fmaf(-2.f, qc, c.w);  // |c|^2 - 2 q.c
    int s = sbase + j;
    bool lt0 = d < d0, lt1 = d < d1, lt2 = d < d2;
    i2 = lt1 ? i1 : (lt2 ? s : i2);
    d2 = lt1 ? d1 : (lt2 ? d : d2);
    i1 = lt0 ? i0 : (lt1 ? s : i1);
    d1 = lt0 ? d0 : (lt1 ? d : d1);
    i0 = lt0 ? s : i0;
    d0 = lt0 ? d : d0;
  }

  __shared__ float dsh[8][64][3];
  __shared__ int   ish[8][64][3];
  dsh[chunk][lane][0] = d0; dsh[chunk][lane][1] = d1; dsh[chunk][lane][2] = d2;
  ish[chunk][lane][0] = i0; ish[chunk][lane][1] = i1; ish[chunk][lane][2] = i2;
  __syncthreads();

  if (t < 64) {
    float e0 = 3e38f, e1 = 3e38f, e2 = 3e38f;
    int j0 = 0, j1 = 0, j2 = 0;
#pragma unroll
    for (int c = 0; c < 8; c++) {
#pragma unroll
      for (int k = 0; k < 3; k++) {
        float d = dsh[c][t][k];
        int s = ish[c][t][k];
        bool lt0 = d < e0, lt1 = d < e1, lt2 = d < e2;
        j2 = lt1 ? j1 : (lt2 ? s : j2);
        e2 = lt1 ? e1 : (lt2 ? d : e2);
        j1 = lt0 ? j0 : (lt1 ? s : j1);
        e1 = lt0 ? e0 : (lt1 ? d : e1);
        j0 = lt0 ? s : j0;
        e0 = lt0 ? d : e0;
      }
    }
    float qq = px * px + py * py + pz * pz;
    float r0 = 1.f / (e0 + qq + 1e-8f);
    float r1 = 1.f / (e1 + qq + 1e-8f);
    float r2 = 1.f / (e2 + qq + 1e-8f);
    float rs = 1.f / (r0 + r1 + r2);
    int base = (b * NPTS + n) * 3;
    nidx[base + 0] = j0; nidx[base + 1] = j1; nidx[base + 2] = j2;
    nw[base + 0] = r0 * rs; nw[base + 1] = r1 * rs; nw[base + 2] = r2 * rs;
  }
}

// ---------------- pack points1 (B,C1,N) fp32 -> Xp[b][n][0..127] bf16 ----------------
__global__ __launch_bounds__(256) void pack_p1_kernel(
    const float* __restrict__ p1, unsigned short* __restrict__ Xp) {
  __shared__ unsigned short tile[64][136];
  int b = blockIdx.y, n0 = blockIdx.x * 64;
  int t = threadIdx.x;
  int nn = t & 63, c4 = t >> 6;
#pragma unroll
  for (int i = 0; i < 32; i++) {
    int c = i * 4 + c4;
    tile[nn][c] = f2bf(p1[((size_t)b * C1 + c) * NPTS + n0 + nn]);
  }
  __syncthreads();
  int n = t >> 2;
#pragma unroll
  for (int j = 0; j < 4; j++) {
    int ch = (t & 3) + j * 4;
    uint4 v = *(const uint4*)&tile[n][ch * 8];
    *(uint4*)&Xp[((size_t)b * NPTS + n0 + n) * CIN + ch * 8] = v;
  }
}

// ---------------- interpolation -> Xp[b][n][128..383] bf16 ----------------
__global__ __launch_bounds__(256) void interp_kernel(
    const float* __restrict__ p2t, const int* __restrict__ nidx,
    const float* __restrict__ nw, unsigned short* __restrict__ Xp) {
  const int PTS = 8;
  int bid = blockIdx.x;
  int b = bid / (NPTS / PTS);
  int p0 = (bid % (NPTS / PTS)) * PTS;
  int c = threadIdx.x;
  const float* base = p2t + (size_t)b * SPTS * C2;
#pragma unroll
  for (int k = 0; k < PTS; k++) {
    int p = p0 + k;
    int ib = (b * NPTS + p) * 3;
    int i0 = nidx[ib], i1 = nidx[ib + 1], i2 = nidx[ib + 2];
    float w0v = nw[ib], w1v = nw[ib + 1], w2v = nw[ib + 2];
    float v = w0v * base[(size_t)i0 * C2 + c] +
              w1v * base[(size_t)i1 * C2 + c] +
              w2v * base[(size_t)i2 * C2 + c];
    Xp[((size_t)b * NPTS + p) * CIN + C1 + c] = f2bf(v);
  }
}

// ---------------- weights fp32 -> bf16 ----------------
__global__ __launch_bounds__(256) void pack_w_kernel(
    const float* __restrict__ w0, const float* __restrict__ w1,
    unsigned short* __restrict__ Wp) {
  int idx = (blockIdx.x * 256 + threadIdx.x) * 4;
  const float* src = (idx < H0 * CIN) ? (w0 + idx) : (w1 + (idx - H0 * CIN));
  float4 v = *(const float4*)src;
  ushort4 o;
  o.x = f2bf(v.x); o.y = f2bf(v.y); o.z = f2bf(v.z); o.w = f2bf(v.w);
  *(ushort4*)(Wp + idx) = o;
}

// ---------------- MFMA GEMM (m97 structure, 128x128 tile) ----------------
template <int MT, int KD, bool OUT_BF16>
__global__ __launch_bounds__(256) void mfma_gemm_kernel(
    const unsigned short* __restrict__ A, const unsigned short* __restrict__ X,
    const float* __restrict__ bias, void* __restrict__ Yv) {
  __shared__ unsigned short As[128 * 32];
  __shared__ unsigned short Bs[128 * 32];
  int b = blockIdx.z;
  int n0 = blockIdx.x * 128;
  int o0 = blockIdx.y * 128;
  int t = threadIdx.x;
  int lane = t & 63;
  int w = __builtin_amdgcn_readfirstlane(t >> 6);
  int mhalf = (w & 1) * 64, nhalf = (w >> 1) * 64;
  const unsigned short* Xb = X + (size_t)b * NPTS * KD;

  f32x4 acc[4][4] = {};

  int rA = lane >> 2;
  int cofs = (lane & 3) * 8;

  for (int k0 = 0; k0 < KD; k0 += 32) {
#pragma unroll
    for (int q = 0; q < 2; q++) {
      int r0 = w * 32 + q * 16;
      const unsigned short* ga = A + (size_t)(o0 + r0 + rA) * KD + k0 + cofs;
      __builtin_amdgcn_global_load_lds(
          (const __attribute__((address_space(1))) void*)ga,
          (__attribute__((address_space(3))) void*)(As + r0 * 32), 16, 0, 0);
      const unsigned short* gb = Xb + (size_t)(n0 + r0 + rA) * KD + k0 + cofs;
      __builtin_amdgcn_global_load_lds(
          (const __attribute__((address_space(1))) void*)gb,
          (__attribute__((address_space(3))) void*)(Bs + r0 * 32), 16, 0, 0);
    }
    __syncthreads();

    bf16x8 af[4], bfr[4];
    int mi = lane & 15, kq = (lane >> 4) * 8;
#pragma unroll
    for (int i = 0; i < 4; i++) {
      af[i]  = *(const bf16x8*)(As + (mhalf + i * 16 + mi) * 32 + kq);
      bfr[i] = *(const bf16x8*)(Bs + (nhalf + i * 16 + mi) * 32 + kq);
    }
#pragma unroll
    for (int mt = 0; mt < 4; mt++)
#pragma unroll
      for (int nt = 0; nt < 4; nt++)
        acc[mt][nt] = __builtin_amdgcn_mfma_f32_16x16x32_bf16(
            af[mt], bfr[nt], acc[mt][nt], 0, 0, 0);
    __syncthreads();
  }

  int mi = lane & 15;
  int rq = (lane >> 4) * 4;
#pragma unroll
  for (int mt = 0; mt < 4; mt++) {
#pragma unroll
    for (int r = 0; r < 4; r++) {
      int m = o0 + mhalf + mt * 16 + rq + r;
      float bv = bias[m];
#pragma unroll
      for (int nt = 0; nt < 4; nt++) {
        int n = n0 + nhalf + nt * 16 + mi;
        float v = acc[mt][nt][r] + bv;
        if constexpr (OUT_BF16) {
          unsigned short* Y = (unsigned short*)Yv + (size_t)b * MT * NPTS;
          Y[(size_t)m * NPTS + n] = f2bf(v);
        } else {
          float* Y = (float*)Yv + (size_t)b * MT * NPTS;
          Y[(size_t)m * NPTS + n] = v;
        }
      }
    }
  }
}

// ---------------- BN stats over bf16 (B,C,N) ----------------
template <int C>
__global__ __launch_bounds__(256) void bn_stats_bf16_kernel(
    const unsigned short* __restrict__ Y, const float* __restrict__ gamma,
    const float* __restrict__ beta, float* __restrict__ a, float* __restrict__ s) {
  int o = blockIdx.x;
  int t = threadIdx.x;
  float sum = 0.f, sq = 0.f;
  for (int b = 0; b < BATCH; b++) {
    const unsigned short* p = Y + ((size_t)b * C + o) * NPTS;
    for (int n = t * 4; n < NPTS; n += 1024) {
      ushort4 v = *(const ushort4*)(p + n);
      float x0 = bf2f(v.x), x1 = bf2f(v.y), x2 = bf2f(v.z), x3 = bf2f(v.w);
      sum += x0 + x1 + x2 + x3;
      sq += x0 * x0 + x1 * x1 + x2 * x2 + x3 * x3;
    }
  }
  __shared__ float r1[256], r2[256];
  r1[t] = sum; r2[t] = sq;
  __syncthreads();
  for (int off = 128; off > 0; off >>= 1) {
    if (t < off) { r1[t] += r1[t + off]; r2[t] += r2[t + off]; }
    __syncthreads();
  }
  if (t == 0) {
    float inv = 1.f / (float)(BATCH * NPTS);
    float mean = r1[0] * inv;
    float var = r2[0] * inv - mean * mean;
    float ia = gamma[o] * rsqrtf(var + 1e-5f);
    a[o] = ia;
    s[o] = beta[o] - mean * ia;
  }
}

// ---------------- BN stats over fp32 (B,C,N) ----------------
template <int C>
__global__ __launch_bounds__(256) void bn_stats_kernel(
    const float* __restrict__ Y, const float* __restrict__ gamma,
    const float* __restrict__ beta, float* __restrict__ a, float* __restrict__ s) {
  int o = blockIdx.x;
  int t = threadIdx.x;
  float sum = 0.f, sq = 0.f;
  for (int b = 0; b < BATCH; b++) {
    const float* p = Y + ((size_t)b * C + o) * NPTS;
    for (int n = t * 4; n < NPTS; n += 1024) {
      float4 v = *(const float4*)(p + n);
      sum += v.x + v.y + v.z + v.w;
      sq += v.x * v.x + v.y * v.y + v.z * v.z + v.w * v.w;
    }
  }
  __shared__ float r1[256], r2[256];
  r1[t] = sum; r2[t] = sq;
  __syncthreads();
  for (int off = 128; off > 0; off >>= 1) {
    if (t < off) { r1[t] += r1[t + off]; r2[t] += r2[t + off]; }
    __syncthreads();
  }
  if (t == 0) {
    float inv = 1.f / (float)(BATCH * NPTS);
    float mean = r1[0] * inv;
    float var = r2[0] * inv - mean * mean;
    float ia = gamma[o] * rsqrtf(var + 1e-5f);
    a[o] = ia;
    s[o] = beta[o] - mean * ia;
  }
}

// ---------------- BN0 apply + ReLU + transpose ----------------
__global__ __launch_bounds__(256) void bn0_apply_kernel(
    const unsigned short* __restrict__ Y0, const float* __restrict__ a,
    const float* __restrict__ s, unsigned short* __restrict__ X1) {
  __shared__ unsigned short tile[64][80];
  int b = blockIdx.z, o0 = blockIdx.y * 64, n0 = blockIdx.x * 64;
  int t = threadIdx.x;
  int nn = t & 63, o4 = t >> 6;
#pragma unroll
  for (int i = 0; i < 16; i++) {
    int o = i * 4 + o4;
    float v = bf2f(Y0[((size_t)b * H0 + o0 + o) * NPTS + n0 + nn]);
    v = fmaxf(v * a[o0 + o] + s[o0 + o], 0.f);
    tile[nn][o] = f2bf(v);
  }
  __syncthreads();
  int n = t >> 2;
#pragma unroll
  for (int j = 0; j < 2; j++) {
    int ch = (t & 3) + j * 4;
    uint4 v = *(const uint4*)&tile[n][ch * 8];
    *(uint4*)&X1[((size_t)b * NPTS + n0 + n) * H0 + o0 + ch * 8] = v;
  }
}

// ---------------- final BN+ReLU in-place on d_out ----------------
__global__ __launch_bounds__(256) void bn_apply_kernel(
    float* __restrict__ Y, const float* __restrict__ a, const float* __restrict__ s) {
  int idx = blockIdx.x * 256 + threadIdx.x;
  int i = idx * 4;
  int c = (i >> 13) & (H1 - 1);
  float ia = a[c], sh = s[c];
  float4 v = *(float4*)(Y + i);
  v.x = fmaxf(v.x * ia + sh, 0.f);
  v.y = fmaxf(v.y * ia + sh, 0.f);
  v.z = fmaxf(v.z * ia + sh, 0.f);
  v.w = fmaxf(v.w * ia + sh, 0.f);
  *(float4*)(Y + i) = v;
}

extern "C" void kernel_launch(void* const* d_in, const int* in_sizes, int n_in,
                              void* d_out, int out_size, void* d_ws, size_t ws_size,
                              hipStream_t stream) {
  const float* xyz1    = (const float*)d_in[0];
  const float* xyz2    = (const float*)d_in[1];
  const float* points1 = (const float*)d_in[2];
  const float* points2 = (const float*)d_in[3];
  const float* w0      = (const float*)d_in[4];
  const float* b0      = (const float*)d_in[5];
  const float* gamma0  = (const float*)d_in[6];
  const float* beta0   = (const float*)d_in[7];
  const float* w1      = (const float*)d_in[8];
  const float* b1      = (const float*)d_in[9];
  const float* gamma1  = (const float*)d_in[10];
  const float* beta1   = (const float*)d_in[11];
  float* out = (float*)d_out;

  char* ws = (char*)d_ws;
  float* p2t = (float*)ws;                    ws += (size_t)BATCH * SPTS * C2 * 4;
  unsigned short* Xp = (unsigned short*)ws;   ws += (size_t)BATCH * NPTS * CIN * 2;
  unsigned short* Y0 = (unsigned short*)ws;   ws += (size_t)BATCH * H0 * NPTS * 2;
  unsigned short* X1 = (unsigned short*)ws;   ws += (size_t)BATCH * NPTS * H0 * 2;
  unsigned short* Wp = (unsigned short*)ws;   ws += (size_t)(H0 * CIN + H1 * H0) * 2;
  int* nidx = (int*)ws;                       ws += (size_t)BATCH * NPTS * 3 * 4;
  float* nw = (float*)ws;                     ws += (size_t)BATCH * NPTS * 3 * 4;
  float4* xyz2p = (float4*)ws;                ws += (size_t)BATCH * SPTS * 16;
  float* a0 = (float*)ws;                     ws += 1024;
  float* s0 = (float*)ws;                     ws += 1024;
  float* a1 = (float*)ws;                     ws += 1024;
  float* s1 = (float*)ws;                     ws += 1024;
  (void)ws_size; (void)in_sizes; (void)n_in; (void)out_size;

  transpose_p2_kernel<<<dim3(SPTS / 64, C2 / 64, BATCH), 256, 0, stream>>>(points2, p2t);
  prepack_xyz2_kernel<<<dim3(BATCH * SPTS / 256), 256, 0, stream>>>(xyz2, xyz2p);
  knn_kernel<<<dim3(NPTS / 64, BATCH), 512, 0, stream>>>(xyz1, xyz2p, nidx, nw);
  pack_p1_kernel<<<dim3(NPTS / 64, BATCH), 256, 0, stream>>>(points1, Xp);
  interp_kernel<<<dim3(BATCH * NPTS / 8), 256, 0, stream>>>(p2t, nidx, nw, Xp);
  pack_w_kernel<<<dim3((H0 * CIN + H1 * H0) / 1024), 256, 0, stream>>>(w0, w1, Wp);

  mfma_gemm_kernel<H0, CIN, true><<<dim3(NPTS / 128, H0 / 128, BATCH), 256, 0, stream>>>(
      Wp, Xp, b0, Y0);
  bn_stats_bf16_kernel<H0><<<H0, 256, 0, stream>>>(Y0, gamma0, beta0, a0, s0);
  bn0_apply_kernel<<<dim3(NPTS / 64, H0 / 64, BATCH), 256, 0, stream>>>(Y0, a0, s0, X1);
  mfma_gemm_kernel<H1, H0, false><<<dim3(NPTS / 128, H1 / 128, BATCH), 256, 0, stream>>>(
      Wp + H0 * CIN, X1, b1, out);
  bn_stats_kernel<H1><<<H1, 256, 0, stream>>>(out, gamma1, beta1, a1, s1);
  bn_apply_kernel<<<dim3(BATCH * H1 * NPTS / 1024), 256, 0, stream>>>(out, a1, s1);
}

// Round 5
// 197.415 us; speedup vs baseline: 2.5016x; 1.1018x over previous
//
#include <hip/hip_runtime.h>
#include <hip/hip_bf16.h>

#define BATCH 4
#define NPTS  8192
#define SPTS  2048
#define C1    128
#define C2    256
#define CIN   384   // C1+C2
#define H0    256
#define H1    128

typedef __attribute__((ext_vector_type(8))) short bf16x8;
typedef __attribute__((ext_vector_type(4))) float f32x4;

__device__ __forceinline__ unsigned short f2bf(float x) {
  union { float f; unsigned u; } v; v.f = x;
  unsigned r = v.u + 0x7fff + ((v.u >> 16) & 1);   // RNE
  return (unsigned short)(r >> 16);
}
__device__ __forceinline__ float bf2f(unsigned short u) {
  union { unsigned u; float f; } v; v.u = ((unsigned)u) << 16; return v.f;
}

// ---------------- fused prep: all input-only packing in one launch ----------------
// seg A [0,512):    transpose points2 (B,C2,S) fp32 -> p2tb (B,S,C2) bf16
// seg B [512,1024): pack points1 (B,C1,N) fp32 -> Xp[b][n][0..127] bf16
// seg C [1024,1056): prepack xyz2 (B,3,S) -> float4 (x,y,z,|c|^2)
// seg D [1056,1184): weights fp32 -> bf16 (Wp0 256x384, then Wp1 128x256)
__global__ __launch_bounds__(256) void prep_kernel(
    const float* __restrict__ p2, unsigned short* __restrict__ p2tb,
    const float* __restrict__ xyz2, float4* __restrict__ xp,
    const float* __restrict__ w0, const float* __restrict__ w1,
    unsigned short* __restrict__ Wp,
    const float* __restrict__ p1, unsigned short* __restrict__ Xp) {
  __shared__ unsigned short shmem[64 * 136];
  int bid = blockIdx.x;
  int t = threadIdx.x;

  if (bid < 512) {  // ---- transpose p2 -> bf16 ----
    int b = bid >> 7, rem = bid & 127;
    int s0 = (rem >> 2) * 64, c0 = (rem & 3) * 64;
    const float* src = p2 + (size_t)b * C2 * SPTS;
    int ss = t & 63, cseg = t >> 6;
#pragma unroll
    for (int i = 0; i < 16; i++) {
      int cc = cseg + i * 4;
      shmem[ss * 72 + cc] = f2bf(src[(size_t)(c0 + cc) * SPTS + s0 + ss]);
    }
    __syncthreads();
    int s = t >> 2, chunk = t & 3;
    uint4 v0 = *(const uint4*)&shmem[s * 72 + chunk * 16];
    uint4 v1 = *(const uint4*)&shmem[s * 72 + chunk * 16 + 8];
    unsigned short* dst = p2tb + (size_t)b * SPTS * C2 + (size_t)(s0 + s) * C2 + c0 + chunk * 16;
    *(uint4*)dst = v0;
    *(uint4*)(dst + 8) = v1;
  } else if (bid < 1024) {  // ---- pack p1 ----
    int b2 = bid - 512;
    int b = b2 >> 7, n0 = (b2 & 127) * 64;
    int nn = t & 63, c4 = t >> 6;
#pragma unroll
    for (int i = 0; i < 32; i++) {
      int c = i * 4 + c4;
      shmem[nn * 136 + c] = f2bf(p1[((size_t)b * C1 + c) * NPTS + n0 + nn]);
    }
    __syncthreads();
    int n = t >> 2;
#pragma unroll
    for (int j = 0; j < 4; j++) {
      int ch = (t & 3) + j * 4;
      uint4 v = *(const uint4*)&shmem[n * 136 + ch * 8];
      *(uint4*)&Xp[((size_t)b * NPTS + n0 + n) * CIN + ch * 8] = v;
    }
  } else if (bid < 1056) {  // ---- prepack xyz2 ----
    int idx = (bid - 1024) * 256 + t;
    int b = idx >> 11, s = idx & (SPTS - 1);
    const float* x2 = xyz2 + (size_t)b * 3 * SPTS;
    float x = x2[s], y = x2[SPTS + s], z = x2[2 * SPTS + s];
    xp[idx] = make_float4(x, y, z, x * x + y * y + z * z);
  } else {  // ---- pack weights ----
    int idx = ((bid - 1056) * 256 + t) * 4;
    const float* src = (idx < H0 * CIN) ? (w0 + idx) : (w1 + (idx - H0 * CIN));
    float4 v = *(const float4*)src;
    ushort4 o;
    o.x = f2bf(v.x); o.y = f2bf(v.y); o.z = f2bf(v.z); o.w = f2bf(v.w);
    *(ushort4*)(Wp + idx) = o;
  }
}

// branchless top-3 insert: distances via fmin/fmed3, indices via cndmask
#define INS3(d, s, e0, e1, e2, j0, j1, j2)                        \
  {                                                               \
    bool lt0 = (d) < (e0), lt1 = (d) < (e1), lt2 = (d) < (e2);    \
    j2 = lt1 ? (j1) : (lt2 ? (s) : (j2));                         \
    j1 = lt0 ? (j0) : (lt1 ? (s) : (j1));                         \
    j0 = lt0 ? (s) : (j0);                                        \
    e2 = __builtin_amdgcn_fmed3f((d), (e1), (e2));                \
    e1 = __builtin_amdgcn_fmed3f((d), (e0), (e1));                \
    e0 = fminf((d), (e0));                                        \
  }

// ---------------- 3-NN search v4: 16 waves/block, 128-cand chunks, 2-stage merge ----------------
// Rank on d' = |c|^2 - 2 q.c (per-query |q|^2 offset preserves ordering).
__global__ __launch_bounds__(1024) void knn_kernel(
    const float* __restrict__ xyz1, const float4* __restrict__ xp,
    int* __restrict__ nidx, float* __restrict__ nw) {
  int b = blockIdx.y;
  int t = threadIdx.x;
  int lane = t & 63;
  int w = __builtin_amdgcn_readfirstlane(t >> 6);  // 0..15, wave-uniform
  int n = blockIdx.x * 64 + lane;
  const float* x1 = xyz1 + (size_t)b * 3 * NPTS;
  float px = x1[n], py = x1[NPTS + n], pz = x1[2 * NPTS + n];

  const int CHUNK = SPTS / 16;  // 128
  int sbase = w * CHUNK;
  const float4* cp = xp + (size_t)b * SPTS + sbase;

  float d0 = 3e38f, d1 = 3e38f, d2 = 3e38f;
  int i0 = 0, i1 = 0, i2 = 0;
#pragma unroll 8
  for (int j = 0; j < CHUNK; j++) {
    float4 c = cp[j];  // wave-uniform address -> scalar load
    float qc = fmaf(py, c.y, px * c.x);
    qc = fmaf(pz, c.z, qc);
    float d = fmaf(-2.f, qc, c.w);
    int s = sbase + j;
    INS3(d, s, d0, d1, d2, i0, i1, i2);
  }

  __shared__ float dsh[16][64][3];
  __shared__ int   ish[16][64][3];
  dsh[w][lane][0] = d0; dsh[w][lane][1] = d1; dsh[w][lane][2] = d2;
  ish[w][lane][0] = i0; ish[w][lane][1] = i1; ish[w][lane][2] = i2;
  __syncthreads();

  // stage B: 4 groups merge 4 lists each (threads 0..255)
  if (t < 256) {
    int g = t >> 6, q = t & 63;
    float e0 = 3e38f, e1 = 3e38f, e2 = 3e38f;
    int j0 = 0, j1 = 0, j2 = 0;
#pragma unroll
    for (int c = 0; c < 4; c++) {
#pragma unroll
      for (int k = 0; k < 3; k++) {
        float d = dsh[4 * g + c][q][k];
        int s = ish[4 * g + c][q][k];
        INS3(d, s, e0, e1, e2, j0, j1, j2);
      }
    }
    dsh[4 * g][q][0] = e0; dsh[4 * g][q][1] = e1; dsh[4 * g][q][2] = e2;
    ish[4 * g][q][0] = j0; ish[4 * g][q][1] = j1; ish[4 * g][q][2] = j2;
  }
  __syncthreads();

  // stage C: final merge of 4 lists (threads 0..63 == wave 0, which owns px/py/pz for n)
  if (t < 64) {
    float e0 = 3e38f, e1 = 3e38f, e2 = 3e38f;
    int j0 = 0, j1 = 0, j2 = 0;
#pragma unroll
    for (int c = 0; c < 4; c++) {
#pragma unroll
      for (int k = 0; k < 3; k++) {
        float d = dsh[4 * c][t][k];
        int s = ish[4 * c][t][k];
        INS3(d, s, e0, e1, e2, j0, j1, j2);
      }
    }
    float qq = px * px + py * py + pz * pz;
    float r0 = 1.f / (e0 + qq + 1e-8f);
    float r1 = 1.f / (e1 + qq + 1e-8f);
    float r2 = 1.f / (e2 + qq + 1e-8f);
    float rs = 1.f / (r0 + r1 + r2);
    int base = (b * NPTS + n) * 3;
    nidx[base + 0] = j0; nidx[base + 1] = j1; nidx[base + 2] = j2;
    nw[base + 0] = r0 * rs; nw[base + 1] = r1 * rs; nw[base + 2] = r2 * rs;
  }
}

// ---------------- interpolation (bf16 gather) -> Xp[b][n][128..383] bf16 ----------------
__global__ __launch_bounds__(256) void interp_kernel(
    const unsigned short* __restrict__ p2tb, const int* __restrict__ nidx,
    const float* __restrict__ nw, unsigned short* __restrict__ Xp) {
  const int PTS = 8;
  int bid = blockIdx.x;
  int b = bid / (NPTS / PTS);
  int p0 = (bid % (NPTS / PTS)) * PTS;
  int c = threadIdx.x;
  const unsigned short* base = p2tb + (size_t)b * SPTS * C2;
#pragma unroll
  for (int k = 0; k < PTS; k++) {
    int p = p0 + k;
    int ib = (b * NPTS + p) * 3;
    int i0 = nidx[ib], i1 = nidx[ib + 1], i2 = nidx[ib + 2];
    float w0v = nw[ib], w1v = nw[ib + 1], w2v = nw[ib + 2];
    float v = w0v * bf2f(base[(size_t)i0 * C2 + c]) +
              w1v * bf2f(base[(size_t)i1 * C2 + c]) +
              w2v * bf2f(base[(size_t)i2 * C2 + c]);
    Xp[((size_t)b * NPTS + p) * CIN + C1 + c] = f2bf(v);
  }
}

// ---------------- MFMA GEMM (m97 structure, 128x128 tile) ----------------
template <int MT, int KD, bool OUT_BF16>
__global__ __launch_bounds__(256) void mfma_gemm_kernel(
    const unsigned short* __restrict__ A, const unsigned short* __restrict__ X,
    const float* __restrict__ bias, void* __restrict__ Yv) {
  __shared__ unsigned short As[128 * 32];
  __shared__ unsigned short Bs[128 * 32];
  int b = blockIdx.z;
  int n0 = blockIdx.x * 128;
  int o0 = blockIdx.y * 128;
  int t = threadIdx.x;
  int lane = t & 63;
  int w = __builtin_amdgcn_readfirstlane(t >> 6);
  int mhalf = (w & 1) * 64, nhalf = (w >> 1) * 64;
  const unsigned short* Xb = X + (size_t)b * NPTS * KD;

  f32x4 acc[4][4] = {};

  int rA = lane >> 2;
  int cofs = (lane & 3) * 8;

  for (int k0 = 0; k0 < KD; k0 += 32) {
#pragma unroll
    for (int q = 0; q < 2; q++) {
      int r0 = w * 32 + q * 16;
      const unsigned short* ga = A + (size_t)(o0 + r0 + rA) * KD + k0 + cofs;
      __builtin_amdgcn_global_load_lds(
          (const __attribute__((address_space(1))) void*)ga,
          (__attribute__((address_space(3))) void*)(As + r0 * 32), 16, 0, 0);
      const unsigned short* gb = Xb + (size_t)(n0 + r0 + rA) * KD + k0 + cofs;
      __builtin_amdgcn_global_load_lds(
          (const __attribute__((address_space(1))) void*)gb,
          (__attribute__((address_space(3))) void*)(Bs + r0 * 32), 16, 0, 0);
    }
    __syncthreads();

    bf16x8 af[4], bfr[4];
    int mi = lane & 15, kq = (lane >> 4) * 8;
#pragma unroll
    for (int i = 0; i < 4; i++) {
      af[i]  = *(const bf16x8*)(As + (mhalf + i * 16 + mi) * 32 + kq);
      bfr[i] = *(const bf16x8*)(Bs + (nhalf + i * 16 + mi) * 32 + kq);
    }
#pragma unroll
    for (int mt = 0; mt < 4; mt++)
#pragma unroll
      for (int nt = 0; nt < 4; nt++)
        acc[mt][nt] = __builtin_amdgcn_mfma_f32_16x16x32_bf16(
            af[mt], bfr[nt], acc[mt][nt], 0, 0, 0);
    __syncthreads();
  }

  int mi = lane & 15;
  int rq = (lane >> 4) * 4;
#pragma unroll
  for (int mt = 0; mt < 4; mt++) {
#pragma unroll
    for (int r = 0; r < 4; r++) {
      int m = o0 + mhalf + mt * 16 + rq + r;
      float bv = bias[m];
#pragma unroll
      for (int nt = 0; nt < 4; nt++) {
        int n = n0 + nhalf + nt * 16 + mi;
        float v = acc[mt][nt][r] + bv;
        if constexpr (OUT_BF16) {
          unsigned short* Y = (unsigned short*)Yv + (size_t)b * MT * NPTS;
          Y[(size_t)m * NPTS + n] = f2bf(v);
        } else {
          float* Y = (float*)Yv + (size_t)b * MT * NPTS;
          Y[(size_t)m * NPTS + n] = v;
        }
      }
    }
  }
}

// ---------------- BN stats over bf16 (B,C,N) ----------------
template <int C>
__global__ __launch_bounds__(256) void bn_stats_bf16_kernel(
    const unsigned short* __restrict__ Y, const float* __restrict__ gamma,
    const float* __restrict__ beta, float* __restrict__ a, float* __restrict__ s) {
  int o = blockIdx.x;
  int t = threadIdx.x;
  float sum = 0.f, sq = 0.f;
  for (int b = 0; b < BATCH; b++) {
    const unsigned short* p = Y + ((size_t)b * C + o) * NPTS;
    for (int n = t * 4; n < NPTS; n += 1024) {
      ushort4 v = *(const ushort4*)(p + n);
      float x0 = bf2f(v.x), x1 = bf2f(v.y), x2 = bf2f(v.z), x3 = bf2f(v.w);
      sum += x0 + x1 + x2 + x3;
      sq += x0 * x0 + x1 * x1 + x2 * x2 + x3 * x3;
    }
  }
  __shared__ float r1[256], r2[256];
  r1[t] = sum; r2[t] = sq;
  __syncthreads();
  for (int off = 128; off > 0; off >>= 1) {
    if (t < off) { r1[t] += r1[t + off]; r2[t] += r2[t + off]; }
    __syncthreads();
  }
  if (t == 0) {
    float inv = 1.f / (float)(BATCH * NPTS);
    float mean = r1[0] * inv;
    float var = r2[0] * inv - mean * mean;
    float ia = gamma[o] * rsqrtf(var + 1e-5f);
    a[o] = ia;
    s[o] = beta[o] - mean * ia;
  }
}

// ---------------- BN stats over fp32 (B,C,N) ----------------
template <int C>
__global__ __launch_bounds__(256) void bn_stats_kernel(
    const float* __restrict__ Y, const float* __restrict__ gamma,
    const float* __restrict__ beta, float* __restrict__ a, float* __restrict__ s) {
  int o = blockIdx.x;
  int t = threadIdx.x;
  float sum = 0.f, sq = 0.f;
  for (int b = 0; b < BATCH; b++) {
    const float* p = Y + ((size_t)b * C + o) * NPTS;
    for (int n = t * 4; n < NPTS; n += 1024) {
      float4 v = *(const float4*)(p + n);
      sum += v.x + v.y + v.z + v.w;
      sq += v.x * v.x + v.y * v.y + v.z * v.z + v.w * v.w;
    }
  }
  __shared__ float r1[256], r2[256];
  r1[t] = sum; r2[t] = sq;
  __syncthreads();
  for (int off = 128; off > 0; off >>= 1) {
    if (t < off) { r1[t] += r1[t + off]; r2[t] += r2[t + off]; }
    __syncthreads();
  }
  if (t == 0) {
    float inv = 1.f / (float)(BATCH * NPTS);
    float mean = r1[0] * inv;
    float var = r2[0] * inv - mean * mean;
    float ia = gamma[o] * rsqrtf(var + 1e-5f);
    a[o] = ia;
    s[o] = beta[o] - mean * ia;
  }
}

// ---------------- BN0 apply + ReLU + transpose ----------------
__global__ __launch_bounds__(256) void bn0_apply_kernel(
    const unsigned short* __restrict__ Y0, const float* __restrict__ a,
    const float* __restrict__ s, unsigned short* __restrict__ X1) {
  __shared__ unsigned short tile[64][80];
  int b = blockIdx.z, o0 = blockIdx.y * 64, n0 = blockIdx.x * 64;
  int t = threadIdx.x;
  int nn = t & 63, o4 = t >> 6;
#pragma unroll
  for (int i = 0; i < 16; i++) {
    int o = i * 4 + o4;
    float v = bf2f(Y0[((size_t)b * H0 + o0 + o) * NPTS + n0 + nn]);
    v = fmaxf(v * a[o0 + o] + s[o0 + o], 0.f);
    tile[nn][o] = f2bf(v);
  }
  __syncthreads();
  int n = t >> 2;
#pragma unroll
  for (int j = 0; j < 2; j++) {
    int ch = (t & 3) + j * 4;
    uint4 v = *(const uint4*)&tile[n][ch * 8];
    *(uint4*)&X1[((size_t)b * NPTS + n0 + n) * H0 + o0 + ch * 8] = v;
  }
}

// ---------------- final BN+ReLU in-place on d_out ----------------
__global__ __launch_bounds__(256) void bn_apply_kernel(
    float* __restrict__ Y, const float* __restrict__ a, const float* __restrict__ s) {
  int idx = blockIdx.x * 256 + threadIdx.x;
  int i = idx * 4;
  int c = (i >> 13) & (H1 - 1);
  float ia = a[c], sh = s[c];
  float4 v = *(float4*)(Y + i);
  v.x = fmaxf(v.x * ia + sh, 0.f);
  v.y = fmaxf(v.y * ia + sh, 0.f);
  v.z = fmaxf(v.z * ia + sh, 0.f);
  v.w = fmaxf(v.w * ia + sh, 0.f);
  *(float4*)(Y + i) = v;
}

extern "C" void kernel_launch(void* const* d_in, const int* in_sizes, int n_in,
                              void* d_out, int out_size, void* d_ws, size_t ws_size,
                              hipStream_t stream) {
  const float* xyz1    = (const float*)d_in[0];
  const float* xyz2    = (const float*)d_in[1];
  const float* points1 = (const float*)d_in[2];
  const float* points2 = (const float*)d_in[3];
  const float* w0      = (const float*)d_in[4];
  const float* b0      = (const float*)d_in[5];
  const float* gamma0  = (const float*)d_in[6];
  const float* beta0   = (const float*)d_in[7];
  const float* w1      = (const float*)d_in[8];
  const float* b1      = (const float*)d_in[9];
  const float* gamma1  = (const float*)d_in[10];
  const float* beta1   = (const float*)d_in[11];
  float* out = (float*)d_out;

  char* ws = (char*)d_ws;
  unsigned short* p2tb = (unsigned short*)ws;  ws += (size_t)BATCH * SPTS * C2 * 2;   // 4.2 MB
  unsigned short* Xp = (unsigned short*)ws;    ws += (size_t)BATCH * NPTS * CIN * 2;  // 25.2 MB
  unsigned short* Y0 = (unsigned short*)ws;    ws += (size_t)BATCH * H0 * NPTS * 2;   // 16.8 MB
  unsigned short* X1 = (unsigned short*)ws;    ws += (size_t)BATCH * NPTS * H0 * 2;   // 16.8 MB
  unsigned short* Wp = (unsigned short*)ws;    ws += (size_t)(H0 * CIN + H1 * H0) * 2;
  int* nidx = (int*)ws;                        ws += (size_t)BATCH * NPTS * 3 * 4;
  float* nw = (float*)ws;                      ws += (size_t)BATCH * NPTS * 3 * 4;
  float4* xyz2p = (float4*)(((uintptr_t)ws + 15) & ~(uintptr_t)15);
  ws = (char*)xyz2p + (size_t)BATCH * SPTS * 16;
  float* a0 = (float*)ws;                      ws += 1024;
  float* s0 = (float*)ws;                      ws += 1024;
  float* a1 = (float*)ws;                      ws += 1024;
  float* s1 = (float*)ws;                      ws += 1024;
  (void)ws_size; (void)in_sizes; (void)n_in; (void)out_size;

  prep_kernel<<<dim3(1184), 256, 0, stream>>>(points2, p2tb, xyz2, xyz2p,
                                              w0, w1, Wp, points1, Xp);
  knn_kernel<<<dim3(NPTS / 64, BATCH), 1024, 0, stream>>>(xyz1, xyz2p, nidx, nw);
  interp_kernel<<<dim3(BATCH * NPTS / 8), 256, 0, stream>>>(p2tb, nidx, nw, Xp);

  mfma_gemm_kernel<H0, CIN, true><<<dim3(NPTS / 128, H0 / 128, BATCH), 256, 0, stream>>>(
      Wp, Xp, b0, Y0);
  bn_stats_bf16_kernel<H0><<<H0, 256, 0, stream>>>(Y0, gamma0, beta0, a0, s0);
  bn0_apply_kernel<<<dim3(NPTS / 64, H0 / 64, BATCH), 256, 0, stream>>>(Y0, a0, s0, X1);
  mfma_gemm_kernel<H1, H0, false><<<dim3(NPTS / 128, H1 / 128, BATCH), 256, 0, stream>>>(
      Wp + H0 * CIN, X1, b1, out);
  bn_stats_kernel<H1><<<H1, 256, 0, stream>>>(out, gamma1, beta1, a1, s1);
  bn_apply_kernel<<<dim3(BATCH * H1 * NPTS / 1024), 256, 0, stream>>>(out, a1, s1);
}